// Round 5
// baseline (974.206 us; speedup 1.0000x reference)
//
#include <hip/hip_runtime.h>
#include <hip/hip_cooperative_groups.h>

namespace cg = cooperative_groups;

typedef unsigned short ushort_t;
typedef __attribute__((ext_vector_type(8))) short short8;
typedef __attribute__((ext_vector_type(4))) float floatx4;
typedef __attribute__((ext_vector_type(4))) ushort_t us4;

#define BAR() __builtin_amdgcn_s_barrier()
#define WAITVM(n) __builtin_amdgcn_s_waitcnt(0x0F70 | (n))
#define CBARRIER() __asm__ __volatile__("" ::: "memory")

__device__ __forceinline__ ushort_t f2bf(float f) {
  union { float f; unsigned u; } v; v.f = f;
  unsigned r = v.u + 0x7fffu + ((v.u >> 16) & 1u);
  return (ushort_t)(r >> 16);
}
__device__ __forceinline__ float bf2f(short s) {
  union { unsigned u; float f; } v;
  v.u = ((unsigned)(unsigned short)s) << 16;
  return v.f;
}
__device__ __forceinline__ float fast_sigmoid(float x) {
  return 1.f / (1.f + __expf(-x));
}
__device__ __forceinline__ float fast_tanh(float x) {
  return 1.f - 2.f / (__expf(2.f * x) + 1.f);
}

template <int AUX>
__device__ __forceinline__ void gld16x(const void* g, void* l) {
  __builtin_amdgcn_global_load_lds(
      (__attribute__((address_space(1))) void*)g,
      (__attribute__((address_space(3))) void*)l, 16, 0, AUX);
}

// ---- FF staging: 64x64 chunk, 8KB, XOR-8 swizzle ----
__device__ __forceinline__ void stage64(const ushort_t* src, int ldk,
                                        short* dst, int w, int l) {
  int r0 = (w << 3) + (l >> 3);
  int cb0 = (l & 7) ^ (r0 & 7);
  int r1 = 32 + r0;
  int cb1 = (l & 7) ^ (r1 & 7);
  gld16x<0>(src + (size_t)r0 * ldk + (cb0 << 3), dst + (w << 9));
  gld16x<0>(src + (size_t)r1 * ldk + (cb1 << 3), dst + 2048 + (w << 9));
}

__device__ __forceinline__ void compute_chunk64(const short* As, const short* Bs,
                                                floatx4 acc[2][2], int wm,
                                                int wn, int lhi, int llo) {
#pragma unroll
  for (int ks = 0; ks < 2; ++ks) {
    short8 a[2], b[2];
#pragma unroll
    for (int tm = 0; tm < 2; ++tm) {
      int m = (wm << 5) + (tm << 4) + llo;
      int ph = ((ks << 2) + lhi) ^ (m & 7);
      a[tm] = *(const short8*)(As + m * 64 + (ph << 3));
    }
#pragma unroll
    for (int tn = 0; tn < 2; ++tn) {
      int n = (wn << 5) + (tn << 4) + llo;
      int ph = ((ks << 2) + lhi) ^ (n & 7);
      b[tn] = *(const short8*)(Bs + n * 64 + (ph << 3));
    }
#pragma unroll
    for (int tm = 0; tm < 2; ++tm)
#pragma unroll
      for (int tn = 0; tn < 2; ++tn)
        acc[tm][tn] = __builtin_amdgcn_mfma_f32_16x16x32_bf16(
            a[tm], b[tn], acc[tm][tn], 0, 0, 0);
  }
}

__device__ __forceinline__ void ff_epilogue(floatx4 acc[2][2], const float* bias,
                                            ushort_t* outb, float* outf, int act,
                                            int m0, int n0, int wm, int wn,
                                            int lhi, int llo) {
#pragma unroll
  for (int tm = 0; tm < 2; ++tm)
#pragma unroll
    for (int tn = 0; tn < 2; ++tn)
#pragma unroll
      for (int i = 0; i < 4; ++i) {
        int gm = m0 + (wm << 5) + (tm << 4) + (lhi << 2) + i;
        int gn = n0 + (wn << 5) + (tn << 4) + llo;
        float v = acc[tm][tn][i];
        if (bias) v += bias[gn];
        if (act == 0) v = fmaxf(v, 0.f);
        if (outb) outb[((size_t)gm << 10) + gn] = f2bf(v);
        if (outf) outf[((size_t)gm << 10) + gn] = v;
      }
}

__device__ void gemm_stream4(const ushort_t* A, const ushort_t* W, int K,
                             const float* bias, ushort_t* outb, float* outf,
                             int act, char* lds, int w, int l, int wm, int wn,
                             int lhi, int llo, int m0, int n0) {
  short* Ab[4] = {(short*)lds, (short*)(lds + 8192), (short*)(lds + 16384),
                  (short*)(lds + 24576)};
  short* Bb[4] = {(short*)(lds + 32768), (short*)(lds + 40960),
                  (short*)(lds + 49152), (short*)(lds + 57344)};
  floatx4 acc[2][2];
#pragma unroll
  for (int i = 0; i < 2; ++i)
#pragma unroll
    for (int j = 0; j < 2; ++j) acc[i][j] = (floatx4){0.f, 0.f, 0.f, 0.f};
  const ushort_t* Abase = A + (size_t)m0 * K;
  const ushort_t* Bbase = W + (size_t)n0 * K;
  int nc = K >> 6;
#pragma unroll
  for (int c0 = 0; c0 < 3; ++c0) {
    stage64(Abase + (c0 << 6), K, Ab[c0], w, l);
    stage64(Bbase + (c0 << 6), K, Bb[c0], w, l);
  }
  for (int c = 0; c < nc; ++c) {
    int nxt = c + 3;
    if (nxt < nc) {
      stage64(Abase + (nxt << 6), K, Ab[nxt & 3], w, l);
      stage64(Bbase + (nxt << 6), K, Bb[nxt & 3], w, l);
      WAITVM(12);
    } else if (nc - c == 3) {
      WAITVM(8);
    } else if (nc - c == 2) {
      WAITVM(4);
    } else {
      WAITVM(0);
    }
    BAR();
    CBARRIER();
    compute_chunk64(Ab[c & 3], Bb[c & 3], acc, wm, wn, lhi, llo);
    BAR();
  }
  ff_epilogue(acc, bias, outb, outf, act, m0, n0, wm, wn, lhi, llo);
}

// Global two-level barrier (FF phases + final only).
__device__ __forceinline__ void gbar(unsigned* area, unsigned seq, int t, int bid) {
  __syncthreads();
  if (t == 0) {
    __threadfence();
    unsigned old = atomicAdd(&area[(bid & 15) << 4], 1u);
    if (old == (seq << 4) - 1u) atomicAdd(&area[256], 1u);
    while (__hip_atomic_load(&area[256], __ATOMIC_RELAXED,
                             __HIP_MEMORY_SCOPE_AGENT) < (seq << 4))
      __builtin_amdgcn_s_sleep(1);
    __threadfence();
  }
  __syncthreads();
}

// RNN chunk staging: 64 rows x 32 k (4KB). Phys 16B-unit p = r*4 + (s^((r>>1)&3)).
template <int AUX>
__device__ __forceinline__ void stage_chunk(const ushort_t* src, short* slot,
                                            int w, int l) {
  int pu = (w << 6) + l;
  int r = pu >> 2;
  int sg = (pu & 3) ^ ((r >> 1) & 3);
  gld16x<AUX>(src + ((size_t)r << 10) + (sg << 3), slot + (w << 9));
}

struct KP {
  const float *x, *W1, *b1, *W2, *b2, *Wih, *Whh, *bih, *bhh, *Wa, *ba;
  ushort_t *Xb, *W1b, *W2b, *Wihb, *Whhb, *Wsmb, *X1b, *Xlb, *Hb0, *Hb1;
  float *xw, *bias, *pacc, *probs, *hxout;
  unsigned* barrier;
  unsigned* flags;  // 256 flags, 64B apart
};

__global__ __launch_bounds__(256, 1) void fused_rnn(KP p) {
  extern __shared__ char lds[];
  cg::grid_group grid = cg::this_grid();
  const int t = threadIdx.x;
  const int w = t >> 6, l = t & 63;
  const int wm = w >> 1, wn = w & 1;
  const int lhi = l >> 4, llo = l & 15;
  const int bid = blockIdx.x;
  const int m0 = (bid >> 4) << 6, n0 = (bid & 15) << 6;
  const int mgrp = bid >> 4, nblk = bid & 15;
  const int gid = bid * 256 + t;
  const bool doactor = (n0 == 0) && ((w & 1) == 0);

  // ---- phase 0: casts, Wsum, bias, zero pacc + barriers + flags ----
  {
    const float4* xf = (const float4*)p.x;
    const float4* w1f = (const float4*)p.W1;
    const float4* w2f = (const float4*)p.W2;
    const float4* wif = (const float4*)p.Wih;
    const float4* whf = (const float4*)p.Whh;
    for (int i = gid; i < 1048576; i += 65536) {
      float4 v = xf[i];
      us4 o;
      o.x = f2bf(v.x); o.y = f2bf(v.y); o.z = f2bf(v.z); o.w = f2bf(v.w);
      ((us4*)p.Xb)[i] = o;
      float4 u = w1f[i];
      o.x = f2bf(u.x); o.y = f2bf(u.y); o.z = f2bf(u.z); o.w = f2bf(u.w);
      ((us4*)p.W1b)[i] = o;
      if (i < 262144) {
        float4 a = w2f[i];
        o.x = f2bf(a.x); o.y = f2bf(a.y); o.z = f2bf(a.z); o.w = f2bf(a.w);
        ((us4*)p.W2b)[i] = o;
        float4 pp = wif[i];
        o.x = f2bf(pp.x); o.y = f2bf(pp.y); o.z = f2bf(pp.z); o.w = f2bf(pp.w);
        ((us4*)p.Wihb)[i] = o;
        float4 q = whf[i];
        o.x = f2bf(q.x); o.y = f2bf(q.y); o.z = f2bf(q.z); o.w = f2bf(q.w);
        ((us4*)p.Whhb)[i] = o;
        o.x = f2bf(pp.x + q.x); o.y = f2bf(pp.y + q.y);
        o.z = f2bf(pp.z + q.z); o.w = f2bf(pp.w + q.w);
        ((us4*)p.Wsmb)[i] = o;
      }
    }
    p.pacc[gid] = 0.f;
    if (gid < 1024) p.bias[gid] = p.bih[gid] + p.bhh[gid];
    if (gid < 4608) p.barrier[gid] = 0u;
  }
  grid.sync();

  // ---- FF phases ----
  gemm_stream4(p.Xb, p.W1b, 4096, p.b1, p.X1b, nullptr, 0, lds, w, l, wm, wn,
               lhi, llo, m0, n0);
  gbar(p.barrier, 1, t, bid);
  gemm_stream4(p.X1b, p.W2b, 1024, p.b2, p.Xlb, nullptr, 0, lds, w, l, wm, wn,
               lhi, llo, m0, n0);
  gbar(p.barrier, 2, t, bid);
  gemm_stream4(p.Xlb, p.Wihb, 1024, nullptr, nullptr, p.xw, 2, lds, w, l, wm,
               wn, lhi, llo, m0, n0);
  gbar(p.barrier, 3, t, bid);

  // ---- resident Wsum slab (rows n0..n0+63, 128 KB) + Wa in LDS (4 KB) ----
  short* slab = (short*)lds;
  {
    const ushort_t* Wn = p.Wsmb + ((size_t)n0 << 10);
#pragma unroll
    for (int i = 0; i < 32; ++i) {
      int c = t + (i << 8);
      int r = c >> 7, cc = c & 127;
      int pc = (cc & ~7) | ((cc & 7) ^ (r & 7));
      short8 v = *(const short8*)(Wn + ((size_t)r << 10) + (cc << 3));
      *(short8*)(slab + (r << 10) + (pc << 3)) = v;
    }
  }
  short* ring = (short*)(lds + 131072);      // 6 slots x 4KB
  float* walds = (float*)(lds + 155648);     // 1024 floats
  ((float4*)walds)[t] = ((const float4*)p.Wa)[t];
  __syncthreads();

  ushort_t* Hb[2] = {p.Hb0, p.Hb1};
  const float ba0 = p.ba[0];

  int gnb[2], gmv[2];
#pragma unroll
  for (int tn = 0; tn < 2; ++tn) gnb[tn] = n0 + (wn << 5) + (tn << 4) + (lhi << 2);
#pragma unroll
  for (int tm = 0; tm < 2; ++tm) gmv[tm] = m0 + (wm << 5) + (tm << 4) + llo;
  float bias_r[2][4], wa_r[2][4], xw_r[2][2][4];
#pragma unroll
  for (int tn = 0; tn < 2; ++tn)
#pragma unroll
    for (int i = 0; i < 4; ++i) {
      bias_r[tn][i] = p.bias[gnb[tn] + i];
      wa_r[tn][i] = p.Wa[gnb[tn] + i];
    }
#pragma unroll
  for (int tm = 0; tm < 2; ++tm)
#pragma unroll
    for (int tn = 0; tn < 2; ++tn)
#pragma unroll
      for (int i = 0; i < 4; ++i)
        xw_r[tm][tn][i] = p.xw[((size_t)gmv[tm] << 10) + gnb[tn] + i];

  unsigned fl = 0;  // preloaded peer flag (lanes l<16)

  for (int st = 0; st < 64; ++st) {
    // ---- wait for this m-group's producers of h(st-1) ----
    if (st > 0) {
      while (!__all((l >= 16) || (fl >= (unsigned)st))) {
        __builtin_amdgcn_s_sleep(1);
        if (l < 16)
          fl = __hip_atomic_load(&p.flags[((mgrp << 4) | l) << 4],
                                 __ATOMIC_RELAXED, __HIP_MEMORY_SCOPE_AGENT);
      }
    }
    const ushort_t* hbase =
        ((st == 0) ? p.Xlb : Hb[st & 1]) + ((size_t)m0 << 10);
    bool flag = st && !(st & 15);
    floatx4 acc[2][2];  // [tn][tm]
#pragma unroll
    for (int i = 0; i < 2; ++i)
#pragma unroll
      for (int j = 0; j < 2; ++j) acc[i][j] = (floatx4){0.f, 0.f, 0.f, 0.f};
    float sa[2] = {0.f, 0.f};  // actor dot partials

    if (!flag) {
#pragma unroll
      for (int j = 0; j < 4; ++j)
        stage_chunk<17>(hbase + (j << 5), ring + j * 2048, w, l);
#pragma unroll
      for (int c = 0; c < 32; ++c) {
        if (c <= 28) WAITVM(3);
        else if (c == 29) WAITVM(2);
        else if (c == 30) WAITVM(1);
        else WAITVM(0);
        BAR();
        CBARRIER();
        if (c + 4 < 32)
          stage_chunk<17>(hbase + ((c + 4) << 5), ring + ((c + 4) % 6) * 2048,
                          w, l);
        const short* hslot = ring + (c % 6) * 2048;
        short8 afr[2], bfr[2];
#pragma unroll
        for (int tn = 0; tn < 2; ++tn) {
          int na = (wn << 5) + (tn << 4) + llo;
          int u = (c << 2) + lhi;
          int pu = (u & ~7) | ((u & 7) ^ (na & 7));
          afr[tn] = *(const short8*)(slab + (na << 10) + (pu << 3));
        }
#pragma unroll
        for (int tm = 0; tm < 2; ++tm) {
          int mb = (wm << 5) + (tm << 4) + llo;
          bfr[tm] =
              *(const short8*)(hslot + mb * 32 + ((lhi ^ ((mb >> 1) & 3)) << 3));
        }
#pragma unroll
        for (int tn = 0; tn < 2; ++tn)
#pragma unroll
          for (int tm = 0; tm < 2; ++tm)
            acc[tn][tm] = __builtin_amdgcn_mfma_f32_16x16x32_bf16(
                afr[tn], bfr[tm], acc[tn][tm], 0, 0, 0);
        if (doactor) {
          const float* wch = walds + (c << 5) + (lhi << 3);
#pragma unroll
          for (int tm = 0; tm < 2; ++tm)
#pragma unroll
            for (int j = 0; j < 8; ++j)
              sa[tm] += bf2f(bfr[tm][j]) * wch[j];
        }
      }
    } else {
      const ushort_t* wbase = p.Whhb + ((size_t)n0 << 10);
#pragma unroll
      for (int j = 0; j < 2; ++j) {
        stage_chunk<0>(wbase + (j << 5), ring + j * 2048, w, l);
        stage_chunk<17>(hbase + (j << 5), ring + (3 + j) * 2048, w, l);
      }
#pragma unroll
      for (int c = 0; c < 32; ++c) {
        if (c < 31) WAITVM(2);
        else WAITVM(0);
        BAR();
        CBARRIER();
        if (c + 2 < 32) {
          stage_chunk<0>(wbase + ((c + 2) << 5), ring + ((c + 2) % 3) * 2048,
                         w, l);
          stage_chunk<17>(hbase + ((c + 2) << 5),
                          ring + (3 + (c + 2) % 3) * 2048, w, l);
        }
        const short* wslot = ring + (c % 3) * 2048;
        const short* hslot = ring + (3 + c % 3) * 2048;
        short8 afr[2], bfr[2];
#pragma unroll
        for (int tn = 0; tn < 2; ++tn) {
          int na = (wn << 5) + (tn << 4) + llo;
          afr[tn] =
              *(const short8*)(wslot + na * 32 + ((lhi ^ ((na >> 1) & 3)) << 3));
        }
#pragma unroll
        for (int tm = 0; tm < 2; ++tm) {
          int mb = (wm << 5) + (tm << 4) + llo;
          bfr[tm] =
              *(const short8*)(hslot + mb * 32 + ((lhi ^ ((mb >> 1) & 3)) << 3));
        }
#pragma unroll
        for (int tn = 0; tn < 2; ++tn)
#pragma unroll
          for (int tm = 0; tm < 2; ++tm)
            acc[tn][tm] = __builtin_amdgcn_mfma_f32_16x16x32_bf16(
                afr[tn], bfr[tm], acc[tn][tm], 0, 0, 0);
        if (doactor) {
          const float* wch = walds + (c << 5) + (lhi << 3);
#pragma unroll
          for (int tm = 0; tm < 2; ++tm)
#pragma unroll
            for (int j = 0; j < 8; ++j)
              sa[tm] += bf2f(bfr[tm][j]) * wch[j];
        }
      }
    }

    // ---- in-staging actor output: probs[st-1] ----
    if (doactor && st > 0) {
#pragma unroll
      for (int tm = 0; tm < 2; ++tm) {
        float s = sa[tm];
        s += __shfl_xor(s, 16);
        s += __shfl_xor(s, 32);
        if (lhi == 0)
          p.probs[((st - 1) << 10) | (m0 + (wm << 5) + (tm << 4) + llo)] =
              fast_sigmoid(s + ba0);
      }
    }

    // ---- epilogue ----
    bool last = (st == 63);
    ushort_t* Hnext = Hb[(st + 1) & 1];
    float hv[2][2][4];  // [tn][tm][i]
#pragma unroll
    for (int tn = 0; tn < 2; ++tn)
#pragma unroll
      for (int tm = 0; tm < 2; ++tm)
#pragma unroll
        for (int i = 0; i < 4; ++i) {
          float v = acc[tn][tm][i] + bias_r[tn][i];
          if (flag) v += xw_r[tm][tn][i];
          hv[tn][tm][i] = fast_tanh(v);
        }
    if (!last) {
#pragma unroll
      for (int tn = 0; tn < 2; ++tn)
#pragma unroll
        for (int tm = 0; tm < 2; ++tm) {
          unsigned long long pk =
              (unsigned long long)f2bf(hv[tn][tm][0]) |
              ((unsigned long long)f2bf(hv[tn][tm][1]) << 16) |
              ((unsigned long long)f2bf(hv[tn][tm][2]) << 32) |
              ((unsigned long long)f2bf(hv[tn][tm][3]) << 48);
          ushort_t* dst = Hnext + ((size_t)gmv[tm] << 10) + gnb[tn];
          __asm__ __volatile__("global_store_dwordx2 %0, %1, off sc0 sc1"
                               :
                               : "v"(dst), "v"(pk)
                               : "memory");
        }
      WAITVM(0);
      __syncthreads();
      if (t == 0)
        __hip_atomic_store(&p.flags[((mgrp << 4) | nblk) << 4],
                           (unsigned)(st + 1), __ATOMIC_RELAXED,
                           __HIP_MEMORY_SCOPE_AGENT);
      if (l < 16)
        fl = __hip_atomic_load(&p.flags[((mgrp << 4) | l) << 4],
                               __ATOMIC_RELAXED, __HIP_MEMORY_SCOPE_AGENT);
    } else {
#pragma unroll
      for (int tn = 0; tn < 2; ++tn)
#pragma unroll
        for (int tm = 0; tm < 2; ++tm) {
          float4 o = make_float4(hv[tn][tm][0], hv[tn][tm][1], hv[tn][tm][2],
                                 hv[tn][tm][3]);
          *(float4*)(p.hxout + ((size_t)gmv[tm] << 10) + gnb[tn]) = o;
        }
      // probs[63] via atomic reduction on fp32 h
#pragma unroll
      for (int tm = 0; tm < 2; ++tm) {
        float s = 0.f;
#pragma unroll
        for (int tn = 0; tn < 2; ++tn)
#pragma unroll
          for (int i = 0; i < 4; ++i) s += hv[tn][tm][i] * wa_r[tn][i];
        s += __shfl_xor(s, 16);
        s += __shfl_xor(s, 32);
        if (l < 16) atomicAdd(&p.pacc[(63 << 10) + gmv[tm]], s);
      }
      WAITVM(0);
    }
  }

  gbar(p.barrier, 4, t, bid);
  if (gid < 1024) {
    float v = __hip_atomic_load(&p.pacc[(63 << 10) + gid], __ATOMIC_RELAXED,
                                __HIP_MEMORY_SCOPE_AGENT);
    p.probs[(63 << 10) + gid] = fast_sigmoid(v + ba0);
  }
}

extern "C" void kernel_launch(void* const* d_in, const int* in_sizes, int n_in,
                              void* d_out, int out_size, void* d_ws,
                              size_t ws_size, hipStream_t stream) {
  char* ws = (char*)d_ws;
  KP p;
  p.x = (const float*)d_in[0];
  p.W1 = (const float*)d_in[1];
  p.b1 = (const float*)d_in[2];
  p.W2 = (const float*)d_in[3];
  p.b2 = (const float*)d_in[4];
  p.Wih = (const float*)d_in[5];
  p.Whh = (const float*)d_in[6];
  p.bih = (const float*)d_in[7];
  p.bhh = (const float*)d_in[8];
  p.Wa = (const float*)d_in[9];
  p.ba = (const float*)d_in[10];
  p.Xb = (ushort_t*)(ws);
  p.W1b = (ushort_t*)(ws + ((size_t)8 << 20));
  p.W2b = (ushort_t*)(ws + ((size_t)16 << 20));
  p.Wihb = (ushort_t*)(ws + ((size_t)18 << 20));
  p.Whhb = (ushort_t*)(ws + ((size_t)20 << 20));
  p.Wsmb = (ushort_t*)(ws + ((size_t)22 << 20));
  p.X1b = (ushort_t*)(ws + ((size_t)24 << 20));
  p.Xlb = (ushort_t*)(ws + ((size_t)26 << 20));
  p.Hb0 = (ushort_t*)(ws + ((size_t)28 << 20));
  p.Hb1 = (ushort_t*)(ws + ((size_t)30 << 20));
  p.xw = (float*)(ws + ((size_t)32 << 20));
  p.bias = (float*)(ws + ((size_t)36 << 20));
  p.pacc = (float*)(ws + ((size_t)36 << 20) + 4096);
  p.barrier = (unsigned*)(ws + ((size_t)36 << 20) + 4096 + 262144);
  p.flags = p.barrier + 512;
  p.probs = (float*)d_out;
  p.hxout = (float*)d_out + 65536;

  hipFuncSetAttribute((const void*)fused_rnn,
                      hipFuncAttributeMaxDynamicSharedMemorySize, 159744);
  void* args[] = {&p};
  hipLaunchCooperativeKernel((const void*)fused_rnn, dim3(256), dim3(256),
                             args, 159744, stream);
}

// Round 7
// 801.093 us; speedup vs baseline: 1.2161x; 1.2161x over previous
//
#include <hip/hip_runtime.h>
#include <hip/hip_cooperative_groups.h>

namespace cg = cooperative_groups;

typedef unsigned short ushort_t;
typedef __attribute__((ext_vector_type(8))) short short8;
typedef __attribute__((ext_vector_type(4))) float floatx4;
typedef __attribute__((ext_vector_type(4))) ushort_t us4;

#define BAR() __builtin_amdgcn_s_barrier()
// vmcnt split encoding: low 4 bits [3:0], high 2 bits [15:14]
#define WAITVM(n) \
  __builtin_amdgcn_s_waitcnt(0x0F70 | ((n) & 15) | (((n) >> 4) << 14))
#define CBARRIER() __asm__ __volatile__("" ::: "memory")

template <int N>
__device__ __forceinline__ void waitvm() {
  __builtin_amdgcn_s_waitcnt(0x0F70 | (N & 15) | ((N >> 4) << 14));
}

// compile-time for loop
template <int V> struct Int { static constexpr int value = V; };
template <int C, int N, typename F> struct StaticFor {
  __device__ __forceinline__ static void run(F& f) {
    f(Int<C>{});
    StaticFor<C + 1, N, F>::run(f);
  }
};
template <int N, typename F> struct StaticFor<N, N, F> {
  __device__ __forceinline__ static void run(F&) {}
};
template <int N, typename F>
__device__ __forceinline__ void static_for(F&& f) {
  StaticFor<0, N, F>::run(f);
}

// wait count for !flag path at chunk c (binding: h(c) for c<16, w(c) for c>=16)
constexpr int nwait_a(int c) {
  int n = 0;
  if (c < 16) {
    n = 12;
    for (int i2 = c - 12; i2 <= c - 1; ++i2)
      if (i2 >= 0 && i2 + 6 >= 16 && i2 + 6 <= 31) ++n;
  } else {
    for (int i2 = c - 5; i2 <= c - 1; ++i2) {
      if (i2 + 13 <= 31) ++n;
      if (i2 + 6 >= 16 && i2 + 6 <= 31) ++n;
    }
  }
  return n;
}
constexpr int nwait_b(int c) {
  int rem = 31 - c;
  return 2 * (rem < 4 ? rem : 4);
}

__device__ __forceinline__ ushort_t f2bf(float f) {
  union { float f; unsigned u; } v; v.f = f;
  unsigned r = v.u + 0x7fffu + ((v.u >> 16) & 1u);
  return (ushort_t)(r >> 16);
}
__device__ __forceinline__ float fast_sigmoid(float x) {
  return 1.f / (1.f + __expf(-x));
}
__device__ __forceinline__ float fast_tanh(float x) {
  return 1.f - 2.f / (__expf(2.f * x) + 1.f);
}

template <int AUX>
__device__ __forceinline__ void gld16x(const void* g, void* l) {
  __builtin_amdgcn_global_load_lds(
      (__attribute__((address_space(1))) void*)g,
      (__attribute__((address_space(3))) void*)l, 16, 0, AUX);
}

// ---- FF staging: 64x64 chunk, 8KB, XOR-8 swizzle ----
__device__ __forceinline__ void stage64(const ushort_t* src, int ldk,
                                        short* dst, int w, int l) {
  int r0 = (w << 3) + (l >> 3);
  int cb0 = (l & 7) ^ (r0 & 7);
  int r1 = 32 + r0;
  int cb1 = (l & 7) ^ (r1 & 7);
  gld16x<0>(src + (size_t)r0 * ldk + (cb0 << 3), dst + (w << 9));
  gld16x<0>(src + (size_t)r1 * ldk + (cb1 << 3), dst + 2048 + (w << 9));
}

__device__ __forceinline__ void compute_chunk64(const short* As, const short* Bs,
                                                floatx4 acc[2][2], int wm,
                                                int wn, int lhi, int llo) {
#pragma unroll
  for (int ks = 0; ks < 2; ++ks) {
    short8 a[2], b[2];
#pragma unroll
    for (int tm = 0; tm < 2; ++tm) {
      int m = (wm << 5) + (tm << 4) + llo;
      int ph = ((ks << 2) + lhi) ^ (m & 7);
      a[tm] = *(const short8*)(As + m * 64 + (ph << 3));
    }
#pragma unroll
    for (int tn = 0; tn < 2; ++tn) {
      int n = (wn << 5) + (tn << 4) + llo;
      int ph = ((ks << 2) + lhi) ^ (n & 7);
      b[tn] = *(const short8*)(Bs + n * 64 + (ph << 3));
    }
#pragma unroll
    for (int tm = 0; tm < 2; ++tm)
#pragma unroll
      for (int tn = 0; tn < 2; ++tn)
        acc[tm][tn] = __builtin_amdgcn_mfma_f32_16x16x32_bf16(
            a[tm], b[tn], acc[tm][tn], 0, 0, 0);
  }
}

__device__ __forceinline__ void ff_epilogue(floatx4 acc[2][2], const float* bias,
                                            ushort_t* outb, float* outf, int act,
                                            int m0, int n0, int wm, int wn,
                                            int lhi, int llo) {
#pragma unroll
  for (int tm = 0; tm < 2; ++tm)
#pragma unroll
    for (int tn = 0; tn < 2; ++tn)
#pragma unroll
      for (int i = 0; i < 4; ++i) {
        int gm = m0 + (wm << 5) + (tm << 4) + (lhi << 2) + i;
        int gn = n0 + (wn << 5) + (tn << 4) + llo;
        float v = acc[tm][tn][i];
        if (bias) v += bias[gn];
        if (act == 0) v = fmaxf(v, 0.f);
        if (outb) outb[((size_t)gm << 10) + gn] = f2bf(v);
        if (outf) outf[((size_t)gm << 10) + gn] = v;
      }
}

__device__ void gemm_stream4(const ushort_t* A, const ushort_t* W, int K,
                             const float* bias, ushort_t* outb, float* outf,
                             int act, char* lds, int w, int l, int wm, int wn,
                             int lhi, int llo, int m0, int n0) {
  short* Ab[4] = {(short*)lds, (short*)(lds + 8192), (short*)(lds + 16384),
                  (short*)(lds + 24576)};
  short* Bb[4] = {(short*)(lds + 32768), (short*)(lds + 40960),
                  (short*)(lds + 49152), (short*)(lds + 57344)};
  floatx4 acc[2][2];
#pragma unroll
  for (int i = 0; i < 2; ++i)
#pragma unroll
    for (int j = 0; j < 2; ++j) acc[i][j] = (floatx4){0.f, 0.f, 0.f, 0.f};
  const ushort_t* Abase = A + (size_t)m0 * K;
  const ushort_t* Bbase = W + (size_t)n0 * K;
  int nc = K >> 6;
#pragma unroll
  for (int c0 = 0; c0 < 3; ++c0) {
    stage64(Abase + (c0 << 6), K, Ab[c0], w, l);
    stage64(Bbase + (c0 << 6), K, Bb[c0], w, l);
  }
  for (int c = 0; c < nc; ++c) {
    int nxt = c + 3;
    if (nxt < nc) {
      stage64(Abase + (nxt << 6), K, Ab[nxt & 3], w, l);
      stage64(Bbase + (nxt << 6), K, Bb[nxt & 3], w, l);
      WAITVM(12);
    } else if (nc - c == 3) {
      WAITVM(8);
    } else if (nc - c == 2) {
      WAITVM(4);
    } else {
      WAITVM(0);
    }
    BAR();
    CBARRIER();
    compute_chunk64(Ab[c & 3], Bb[c & 3], acc, wm, wn, lhi, llo);
    BAR();
  }
  ff_epilogue(acc, bias, outb, outf, act, m0, n0, wm, wn, lhi, llo);
}

// Global two-level barrier (FF phases + final only).
__device__ __forceinline__ void gbar(unsigned* area, unsigned seq, int t, int bid) {
  __syncthreads();
  if (t == 0) {
    __threadfence();
    unsigned old = atomicAdd(&area[(bid & 15) << 4], 1u);
    if (old == (seq << 4) - 1u) atomicAdd(&area[256], 1u);
    while (__hip_atomic_load(&area[256], __ATOMIC_RELAXED,
                             __HIP_MEMORY_SCOPE_AGENT) < (seq << 4))
      __builtin_amdgcn_s_sleep(1);
    __threadfence();
  }
  __syncthreads();
}

// RNN chunk staging: 64 rows x 32 k (4KB). Phys 16B-unit p = r*4 + (s^((r>>1)&3)).
template <int AUX>
__device__ __forceinline__ void stage_chunk(const ushort_t* src, short* slot,
                                            int w, int l) {
  int pu = (w << 6) + l;
  int r = pu >> 2;
  int sg = (pu & 3) ^ ((r >> 1) & 3);
  gld16x<AUX>(src + ((size_t)r << 10) + (sg << 3), slot + (w << 9));
}

struct KP {
  const float *x, *W1, *b1, *W2, *b2, *Wih, *Whh, *bih, *bhh, *Wa, *ba;
  ushort_t *Xb, *W1b, *W2b, *Wihb, *Whhb, *Wsmb, *X1b, *Xlb, *Hb0, *Hb1;
  float *xw, *bias, *pacc, *probs, *hxout;
  unsigned* barrier;
};

__global__ __launch_bounds__(256, 1) void fused_rnn(KP p) {
  extern __shared__ char lds[];
  cg::grid_group grid = cg::this_grid();
  const int t = threadIdx.x;
  const int w = t >> 6, l = t & 63;
  const int wm = w >> 1, wn = w & 1;
  const int lhi = l >> 4, llo = l & 15;
  const int bid = blockIdx.x;
  const int m0 = (bid >> 4) << 6, n0 = (bid & 15) << 6;
  const int mgrp = bid >> 4, nblk = bid & 15;
  const int gid = bid * 256 + t;

  // ---- phase 0: casts, Wsum, bias, zero pacc + barrier area ----
  {
    const float4* xf = (const float4*)p.x;
    const float4* w1f = (const float4*)p.W1;
    const float4* w2f = (const float4*)p.W2;
    const float4* wif = (const float4*)p.Wih;
    const float4* whf = (const float4*)p.Whh;
    for (int i = gid; i < 1048576; i += 65536) {
      float4 v = xf[i];
      us4 o;
      o.x = f2bf(v.x); o.y = f2bf(v.y); o.z = f2bf(v.z); o.w = f2bf(v.w);
      ((us4*)p.Xb)[i] = o;
      float4 u = w1f[i];
      o.x = f2bf(u.x); o.y = f2bf(u.y); o.z = f2bf(u.z); o.w = f2bf(u.w);
      ((us4*)p.W1b)[i] = o;
      if (i < 262144) {
        float4 a = w2f[i];
        o.x = f2bf(a.x); o.y = f2bf(a.y); o.z = f2bf(a.z); o.w = f2bf(a.w);
        ((us4*)p.W2b)[i] = o;
        float4 pp = wif[i];
        o.x = f2bf(pp.x); o.y = f2bf(pp.y); o.z = f2bf(pp.z); o.w = f2bf(pp.w);
        ((us4*)p.Wihb)[i] = o;
        float4 q = whf[i];
        o.x = f2bf(q.x); o.y = f2bf(q.y); o.z = f2bf(q.z); o.w = f2bf(q.w);
        ((us4*)p.Whhb)[i] = o;
        o.x = f2bf(pp.x + q.x); o.y = f2bf(pp.y + q.y);
        o.z = f2bf(pp.z + q.z); o.w = f2bf(pp.w + q.w);
        ((us4*)p.Wsmb)[i] = o;
      }
    }
    p.pacc[gid] = 0.f;
    if (gid < 1024) p.bias[gid] = p.bih[gid] + p.bhh[gid];
    if (gid < 4608) p.barrier[gid] = 0u;
  }
  grid.sync();

  // ---- FF phases ----
  gemm_stream4(p.Xb, p.W1b, 4096, p.b1, p.X1b, nullptr, 0, lds, w, l, wm, wn,
               lhi, llo, m0, n0);
  gbar(p.barrier, 1, t, bid);
  gemm_stream4(p.X1b, p.W2b, 1024, p.b2, p.Xlb, nullptr, 0, lds, w, l, wm, wn,
               lhi, llo, m0, n0);
  gbar(p.barrier, 2, t, bid);
  gemm_stream4(p.Xlb, p.Wihb, 1024, nullptr, nullptr, p.xw, 2, lds, w, l, wm,
               wn, lhi, llo, m0, n0);
  gbar(p.barrier, 3, t, bid);

  // ---- LDS map: slab 64 KB (Wsum rows n0..n0+63, first 16 ROTATED k-chunks)
  //      hring 14 x 4 KB, wring 8 x 4 KB ----
  short* slab = (short*)lds;
  short* hring = (short*)(lds + 65536);
  short* wring = (short*)(lds + 122880);
  {
    const ushort_t* Wn = p.Wsmb + ((size_t)n0 << 10);
#pragma unroll
    for (int i = 0; i < 16; ++i) {
      int c2 = t + (i << 8);          // 0..4095 units of 8 shorts
      int r = c2 >> 6, u = c2 & 63;   // row, local unit
      int gu = ((nblk << 3) + u) & 127;  // rotated global unit
      int pc = (u & ~7) | ((u & 7) ^ (r & 7));
      short8 v = *(const short8*)(Wn + ((size_t)r << 10) + (gu << 3));
      *(short8*)(slab + (r << 9) + (pc << 3)) = v;
    }
  }
  __syncthreads();

  ushort_t* Hb[2] = {p.Hb0, p.Hb1};
  unsigned* mbar = p.barrier + 320 + (mgrp << 4);

  int gnb[2], gmv[2];
#pragma unroll
  for (int tn = 0; tn < 2; ++tn) gnb[tn] = n0 + (wn << 5) + (tn << 4) + (lhi << 2);
#pragma unroll
  for (int tm = 0; tm < 2; ++tm) gmv[tm] = m0 + (wm << 5) + (tm << 4) + llo;
  float bias_r[2][4], wa_r[2][4], xw_r[2][2][4];
#pragma unroll
  for (int tn = 0; tn < 2; ++tn)
#pragma unroll
    for (int i = 0; i < 4; ++i) {
      bias_r[tn][i] = p.bias[gnb[tn] + i];
      wa_r[tn][i] = p.Wa[gnb[tn] + i];
    }
#pragma unroll
  for (int tm = 0; tm < 2; ++tm)
#pragma unroll
    for (int tn = 0; tn < 2; ++tn)
#pragma unroll
      for (int i = 0; i < 4; ++i)
        xw_r[tm][tn][i] = p.xw[((size_t)gmv[tm] << 10) + gnb[tn] + i];

  const int rot = nblk << 1;  // chunk rotation: start at own k-range
  const float ba0 = p.ba[0];

  for (int st = 0; st < 64; ++st) {
    const ushort_t* hbase =
        ((st == 0) ? p.Xlb : Hb[st & 1]) + ((size_t)m0 << 10);
    bool flag = st && !(st & 15);
    floatx4 acc[2][2];  // [tn][tm]
#pragma unroll
    for (int i = 0; i < 2; ++i)
#pragma unroll
      for (int j = 0; j < 2; ++j) acc[i][j] = (floatx4){0.f, 0.f, 0.f, 0.f};

    if (!flag) {
      // A = Wsum (slab chunks 0..15, L2-streamed 16..31); B = h, ring depth 13
#pragma unroll
      for (int j = 0; j < 13; ++j)
        stage_chunk<17>(hbase + (((rot + j) & 31) << 5), hring + j * 2048, w, l);
      const ushort_t* wsrc = p.Wsmb + ((size_t)n0 << 10);
      static_for<32>([&](auto icc) {
        constexpr int c = decltype(icc)::value;
        waitvm<nwait_a(c)>();
        BAR();
        CBARRIER();
        if (c + 13 < 32)
          stage_chunk<17>(hbase + (((rot + c + 13) & 31) << 5),
                          hring + ((c + 13) % 14) * 2048, w, l);
        if (c + 6 >= 16 && c + 6 < 32)
          stage_chunk<0>(wsrc + (((rot + c + 6) & 31) << 5),
                         wring + ((c + 6 - 16) & 7) * 2048, w, l);
        const short* hslot = hring + (c % 14) * 2048;
        short8 afr[2], bfr[2];
        if (c < 16) {
#pragma unroll
          for (int tn = 0; tn < 2; ++tn) {
            int na = (wn << 5) + (tn << 4) + llo;
            int u = (c << 2) + lhi;
            int pu = (u & ~7) | ((u & 7) ^ (na & 7));
            afr[tn] = *(const short8*)(slab + (na << 9) + (pu << 3));
          }
        } else {
          const short* wslot = wring + ((c - 16) & 7) * 2048;
#pragma unroll
          for (int tn = 0; tn < 2; ++tn) {
            int na = (wn << 5) + (tn << 4) + llo;
            afr[tn] = *(const short8*)(wslot + na * 32 +
                                       ((lhi ^ ((na >> 1) & 3)) << 3));
          }
        }
#pragma unroll
        for (int tm = 0; tm < 2; ++tm) {
          int mb = (wm << 5) + (tm << 4) + llo;
          bfr[tm] =
              *(const short8*)(hslot + mb * 32 + ((lhi ^ ((mb >> 1) & 3)) << 3));
        }
#pragma unroll
        for (int tn = 0; tn < 2; ++tn)
#pragma unroll
          for (int tm = 0; tm < 2; ++tm)
            acc[tn][tm] = __builtin_amdgcn_mfma_f32_16x16x32_bf16(
                afr[tn], bfr[tm], acc[tn][tm], 0, 0, 0);
      });
    } else {
      // A = Whh (cached stream), B = h (sc); paired depth-5
      const ushort_t* wbase = p.Whhb + ((size_t)n0 << 10);
#pragma unroll
      for (int j = 0; j < 5; ++j) {
        int kc = (rot + j) & 31;
        stage_chunk<17>(hbase + (kc << 5), hring + j * 2048, w, l);
        stage_chunk<0>(wbase + (kc << 5), wring + j * 2048, w, l);
      }
      static_for<32>([&](auto icc) {
        constexpr int c = decltype(icc)::value;
        waitvm<nwait_b(c)>();
        BAR();
        CBARRIER();
        if (c + 5 < 32) {
          int kc = (rot + c + 5) & 31;
          stage_chunk<17>(hbase + (kc << 5), hring + ((c + 5) % 14) * 2048, w, l);
          stage_chunk<0>(wbase + (kc << 5), wring + ((c + 5) & 7) * 2048, w, l);
        }
        const short* hslot = hring + (c % 14) * 2048;
        const short* wslot = wring + (c & 7) * 2048;
        short8 afr[2], bfr[2];
#pragma unroll
        for (int tn = 0; tn < 2; ++tn) {
          int na = (wn << 5) + (tn << 4) + llo;
          afr[tn] =
              *(const short8*)(wslot + na * 32 + ((lhi ^ ((na >> 1) & 3)) << 3));
        }
#pragma unroll
        for (int tm = 0; tm < 2; ++tm) {
          int mb = (wm << 5) + (tm << 4) + llo;
          bfr[tm] =
              *(const short8*)(hslot + mb * 32 + ((lhi ^ ((mb >> 1) & 3)) << 3));
        }
#pragma unroll
        for (int tn = 0; tn < 2; ++tn)
#pragma unroll
          for (int tm = 0; tm < 2; ++tm)
            acc[tn][tm] = __builtin_amdgcn_mfma_f32_16x16x32_bf16(
                afr[tn], bfr[tm], acc[tn][tm], 0, 0, 0);
      });
    }

    // ---- epilogue ----
    bool last = (st == 63);
    ushort_t* Hnext = Hb[(st + 1) & 1];
    float hv[2][2][4];  // [tn][tm][i]
#pragma unroll
    for (int tn = 0; tn < 2; ++tn)
#pragma unroll
      for (int tm = 0; tm < 2; ++tm)
#pragma unroll
        for (int i = 0; i < 4; ++i) {
          float v = acc[tn][tm][i] + bias_r[tn][i];
          if (flag) v += xw_r[tm][tn][i];
          hv[tn][tm][i] = fast_tanh(v);
        }
    if (!last) {
#pragma unroll
      for (int tn = 0; tn < 2; ++tn)
#pragma unroll
        for (int tm = 0; tm < 2; ++tm) {
          unsigned long long pk =
              (unsigned long long)f2bf(hv[tn][tm][0]) |
              ((unsigned long long)f2bf(hv[tn][tm][1]) << 16) |
              ((unsigned long long)f2bf(hv[tn][tm][2]) << 32) |
              ((unsigned long long)f2bf(hv[tn][tm][3]) << 48);
          ushort_t* dst = Hnext + ((size_t)gmv[tm] << 10) + gnb[tn];
          __asm__ __volatile__("global_store_dwordx2 %0, %1, off sc0 sc1"
                               :
                               : "v"(dst), "v"(pk)
                               : "memory");
        }
    } else {
#pragma unroll
      for (int tn = 0; tn < 2; ++tn)
#pragma unroll
        for (int tm = 0; tm < 2; ++tm) {
          float4 o = make_float4(hv[tn][tm][0], hv[tn][tm][1], hv[tn][tm][2],
                                 hv[tn][tm][3]);
          *(float4*)(p.hxout + ((size_t)gmv[tm] << 10) + gnb[tn]) = o;
        }
    }
    // actor partial into pacc
#pragma unroll
    for (int tm = 0; tm < 2; ++tm) {
      float s = 0.f;
#pragma unroll
      for (int tn = 0; tn < 2; ++tn)
#pragma unroll
        for (int i = 0; i < 4; ++i) s += hv[tn][tm][i] * wa_r[tn][i];
      s += __shfl_xor(s, 16);
      s += __shfl_xor(s, 32);
      if (l < 16) atomicAdd(&p.pacc[(st << 10) + gmv[tm]], s);
    }

    // ---- m-group barrier (16 blocks) ----
    if (!last) {
      WAITVM(0);
      __syncthreads();
      if (t == 0) {
        atomicAdd(mbar, 1u);
        unsigned tgt = (unsigned)(st + 1) << 4;
        while (__hip_atomic_load(mbar, __ATOMIC_RELAXED,
                                 __HIP_MEMORY_SCOPE_AGENT) < tgt)
          __builtin_amdgcn_s_sleep(1);
      }
      __syncthreads();
    } else {
      WAITVM(0);
    }
  }

  gbar(p.barrier, 4, t, bid);
  p.probs[gid] = fast_sigmoid(p.pacc[gid] + ba0);
}

extern "C" void kernel_launch(void* const* d_in, const int* in_sizes, int n_in,
                              void* d_out, int out_size, void* d_ws,
                              size_t ws_size, hipStream_t stream) {
  char* ws = (char*)d_ws;
  KP p;
  p.x = (const float*)d_in[0];
  p.W1 = (const float*)d_in[1];
  p.b1 = (const float*)d_in[2];
  p.W2 = (const float*)d_in[3];
  p.b2 = (const float*)d_in[4];
  p.Wih = (const float*)d_in[5];
  p.Whh = (const float*)d_in[6];
  p.bih = (const float*)d_in[7];
  p.bhh = (const float*)d_in[8];
  p.Wa = (const float*)d_in[9];
  p.ba = (const float*)d_in[10];
  p.Xb = (ushort_t*)(ws);
  p.W1b = (ushort_t*)(ws + ((size_t)8 << 20));
  p.W2b = (ushort_t*)(ws + ((size_t)16 << 20));
  p.Wihb = (ushort_t*)(ws + ((size_t)18 << 20));
  p.Whhb = (ushort_t*)(ws + ((size_t)20 << 20));
  p.Wsmb = (ushort_t*)(ws + ((size_t)22 << 20));
  p.X1b = (ushort_t*)(ws + ((size_t)24 << 20));
  p.Xlb = (ushort_t*)(ws + ((size_t)26 << 20));
  p.Hb0 = (ushort_t*)(ws + ((size_t)28 << 20));
  p.Hb1 = (ushort_t*)(ws + ((size_t)30 << 20));
  p.xw = (float*)(ws + ((size_t)32 << 20));
  p.bias = (float*)(ws + ((size_t)36 << 20));
  p.pacc = (float*)(ws + ((size_t)36 << 20) + 4096);
  p.barrier = (unsigned*)(ws + ((size_t)36 << 20) + 4096 + 262144);
  p.probs = (float*)d_out;
  p.hxout = (float*)d_out + 65536;

  (void)hipFuncSetAttribute((const void*)fused_rnn,
                            hipFuncAttributeMaxDynamicSharedMemorySize, 155648);
  void* args[] = {&p};
  (void)hipLaunchCooperativeKernel((const void*)fused_rnn, dim3(256), dim3(256),
                                   args, 155648, stream);
}

// Round 8
// 686.081 us; speedup vs baseline: 1.4200x; 1.1676x over previous
//
#include <hip/hip_runtime.h>
#include <hip/hip_cooperative_groups.h>

namespace cg = cooperative_groups;

typedef unsigned short ushort_t;
typedef __attribute__((ext_vector_type(8))) short short8;
typedef __attribute__((ext_vector_type(4))) float floatx4;
typedef __attribute__((ext_vector_type(4))) ushort_t us4;

#define BAR() __builtin_amdgcn_s_barrier()
#define WAITVM(n) \
  __builtin_amdgcn_s_waitcnt(0x0F70 | ((n) & 15) | (((n) >> 4) << 14))
#define CBARRIER() __asm__ __volatile__("" ::: "memory")

template <int N>
__device__ __forceinline__ void waitvm() {
  __builtin_amdgcn_s_waitcnt(0x0F70 | (N & 15) | ((N >> 4) << 14));
}

template <int V> struct Int { static constexpr int value = V; };
template <int C, int N, typename F> struct StaticFor {
  __device__ __forceinline__ static void run(F& f) {
    f(Int<C>{});
    StaticFor<C + 1, N, F>::run(f);
  }
};
template <int N, typename F> struct StaticFor<N, N, F> {
  __device__ __forceinline__ static void run(F&) {}
};
template <int N, typename F>
__device__ __forceinline__ void static_for(F&& f) {
  StaticFor<0, N, F>::run(f);
}

// h-ring (depth 4, 6 slots): at iter c, h(c..c+3) may be outstanding.
constexpr int nwa(int c) { int r = 31 - c; return r < 3 ? r : 3; }
// paired w+h ring (depth 3): pairs (c),(c+1) outstanding -> wait 2.
constexpr int nwb(int c) { return (c == 31) ? 0 : 2; }

__device__ __forceinline__ ushort_t f2bf(float f) {
  union { float f; unsigned u; } v; v.f = f;
  unsigned r = v.u + 0x7fffu + ((v.u >> 16) & 1u);
  return (ushort_t)(r >> 16);
}
__device__ __forceinline__ float fast_sigmoid(float x) {
  return 1.f / (1.f + __expf(-x));
}
__device__ __forceinline__ float fast_tanh(float x) {
  return 1.f - 2.f / (__expf(2.f * x) + 1.f);
}

template <int AUX>
__device__ __forceinline__ void gld16x(const void* g, void* l) {
  __builtin_amdgcn_global_load_lds(
      (__attribute__((address_space(1))) void*)g,
      (__attribute__((address_space(3))) void*)l, 16, 0, AUX);
}

// ---- FF staging: 64x64 chunk, 8KB, XOR-8 swizzle ----
__device__ __forceinline__ void stage64(const ushort_t* src, int ldk,
                                        short* dst, int w, int l) {
  int r0 = (w << 3) + (l >> 3);
  int cb0 = (l & 7) ^ (r0 & 7);
  int r1 = 32 + r0;
  int cb1 = (l & 7) ^ (r1 & 7);
  gld16x<0>(src + (size_t)r0 * ldk + (cb0 << 3), dst + (w << 9));
  gld16x<0>(src + (size_t)r1 * ldk + (cb1 << 3), dst + 2048 + (w << 9));
}

__device__ __forceinline__ void compute_chunk64(const short* As, const short* Bs,
                                                floatx4 acc[2][2], int wm,
                                                int wn, int lhi, int llo) {
#pragma unroll
  for (int ks = 0; ks < 2; ++ks) {
    short8 a[2], b[2];
#pragma unroll
    for (int tm = 0; tm < 2; ++tm) {
      int m = (wm << 5) + (tm << 4) + llo;
      int ph = ((ks << 2) + lhi) ^ (m & 7);
      a[tm] = *(const short8*)(As + m * 64 + (ph << 3));
    }
#pragma unroll
    for (int tn = 0; tn < 2; ++tn) {
      int n = (wn << 5) + (tn << 4) + llo;
      int ph = ((ks << 2) + lhi) ^ (n & 7);
      b[tn] = *(const short8*)(Bs + n * 64 + (ph << 3));
    }
#pragma unroll
    for (int tm = 0; tm < 2; ++tm)
#pragma unroll
      for (int tn = 0; tn < 2; ++tn)
        acc[tm][tn] = __builtin_amdgcn_mfma_f32_16x16x32_bf16(
            a[tm], b[tn], acc[tm][tn], 0, 0, 0);
  }
}

__device__ __forceinline__ void ff_epilogue(floatx4 acc[2][2], const float* bias,
                                            ushort_t* outb, float* outf, int act,
                                            int m0, int n0, int wm, int wn,
                                            int lhi, int llo) {
#pragma unroll
  for (int tm = 0; tm < 2; ++tm)
#pragma unroll
    for (int tn = 0; tn < 2; ++tn)
#pragma unroll
      for (int i = 0; i < 4; ++i) {
        int gm = m0 + (wm << 5) + (tm << 4) + (lhi << 2) + i;
        int gn = n0 + (wn << 5) + (tn << 4) + llo;
        float v = acc[tm][tn][i];
        if (bias) v += bias[gn];
        if (act == 0) v = fmaxf(v, 0.f);
        if (outb) outb[((size_t)gm << 10) + gn] = f2bf(v);
        if (outf) outf[((size_t)gm << 10) + gn] = v;
      }
}

__device__ void gemm_stream4(const ushort_t* A, const ushort_t* W, int K,
                             const float* bias, ushort_t* outb, float* outf,
                             int act, char* lds, int w, int l, int wm, int wn,
                             int lhi, int llo, int m0, int n0) {
  short* Ab[4] = {(short*)lds, (short*)(lds + 8192), (short*)(lds + 16384),
                  (short*)(lds + 24576)};
  short* Bb[4] = {(short*)(lds + 32768), (short*)(lds + 40960),
                  (short*)(lds + 49152), (short*)(lds + 57344)};
  floatx4 acc[2][2];
#pragma unroll
  for (int i = 0; i < 2; ++i)
#pragma unroll
    for (int j = 0; j < 2; ++j) acc[i][j] = (floatx4){0.f, 0.f, 0.f, 0.f};
  const ushort_t* Abase = A + (size_t)m0 * K;
  const ushort_t* Bbase = W + (size_t)n0 * K;
  int nc = K >> 6;
#pragma unroll
  for (int c0 = 0; c0 < 3; ++c0) {
    stage64(Abase + (c0 << 6), K, Ab[c0], w, l);
    stage64(Bbase + (c0 << 6), K, Bb[c0], w, l);
  }
  for (int c = 0; c < nc; ++c) {
    int nxt = c + 3;
    if (nxt < nc) {
      stage64(Abase + (nxt << 6), K, Ab[nxt & 3], w, l);
      stage64(Bbase + (nxt << 6), K, Bb[nxt & 3], w, l);
      WAITVM(12);
    } else if (nc - c == 3) {
      WAITVM(8);
    } else if (nc - c == 2) {
      WAITVM(4);
    } else {
      WAITVM(0);
    }
    BAR();
    CBARRIER();
    compute_chunk64(Ab[c & 3], Bb[c & 3], acc, wm, wn, lhi, llo);
    BAR();
  }
  ff_epilogue(acc, bias, outb, outf, act, m0, n0, wm, wn, lhi, llo);
}

// Global two-level barrier with full fences.
__device__ __forceinline__ void gbar(unsigned* area, unsigned seq, int t, int bid) {
  __syncthreads();
  if (t == 0) {
    __threadfence();
    unsigned old = atomicAdd(&area[(bid & 15) << 4], 1u);
    if (old == (seq << 4) - 1u) atomicAdd(&area[256], 1u);
    while (__hip_atomic_load(&area[256], __ATOMIC_RELAXED,
                             __HIP_MEMORY_SCOPE_AGENT) < (seq << 4))
      __builtin_amdgcn_s_sleep(1);
    __threadfence();
  }
  __syncthreads();
}

// RNN chunk staging: 64 rows x 32 k (4KB). Phys 16B-unit p = r*4 + (s^((r>>1)&3)).
template <int AUX>
__device__ __forceinline__ void stage_chunk(const ushort_t* src, short* slot,
                                            int w, int l) {
  int pu = (w << 6) + l;
  int r = pu >> 2;
  int sg = (pu & 3) ^ ((r >> 1) & 3);
  gld16x<AUX>(src + ((size_t)r << 10) + (sg << 3), slot + (w << 9));
}

struct KP {
  const float *x, *W1, *b1, *W2, *b2, *Wih, *Whh, *bih, *bhh, *Wa, *ba;
  ushort_t *Xb, *W1b, *W2b, *Wihb, *Whhb, *Wsmb, *X1b, *Xlb, *Hb0, *Hb1;
  float *xw, *bias, *pacc, *probs, *hxout;
  unsigned* barrier;
};

__global__ __launch_bounds__(256, 1) void fused_rnn(KP p) {
  extern __shared__ char lds[];
  cg::grid_group grid = cg::this_grid();
  const int t = threadIdx.x;
  const int w = t >> 6, l = t & 63;
  const int wm = w >> 1, wn = w & 1;
  const int lhi = l >> 4, llo = l & 15;
  const int bid = blockIdx.x;
  // FF mapping (arbitrary):
  const int m0f = (bid >> 4) << 6, n0f = (bid & 15) << 6;
  // RNN mapping: m-group = bid&15 so all 16 peers share bid%8 (one XCD under
  // round-robin dispatch). Verified at runtime; falls back to sc1 if not.
  const int mgrp = bid & 15, nblk = bid >> 4;
  const int m0r = mgrp << 6, n0r = nblk << 6;
  const int gid = bid * 256 + t;

  // ---- phase 0: casts, Wsum, bias, zero pacc + barrier/flag area ----
  {
    const float4* xf = (const float4*)p.x;
    const float4* w1f = (const float4*)p.W1;
    const float4* w2f = (const float4*)p.W2;
    const float4* wif = (const float4*)p.Wih;
    const float4* whf = (const float4*)p.Whh;
    for (int i = gid; i < 1048576; i += 65536) {
      float4 v = xf[i];
      us4 o;
      o.x = f2bf(v.x); o.y = f2bf(v.y); o.z = f2bf(v.z); o.w = f2bf(v.w);
      ((us4*)p.Xb)[i] = o;
      float4 u = w1f[i];
      o.x = f2bf(u.x); o.y = f2bf(u.y); o.z = f2bf(u.z); o.w = f2bf(u.w);
      ((us4*)p.W1b)[i] = o;
      if (i < 262144) {
        float4 a = w2f[i];
        o.x = f2bf(a.x); o.y = f2bf(a.y); o.z = f2bf(a.z); o.w = f2bf(a.w);
        ((us4*)p.W2b)[i] = o;
        float4 pp = wif[i];
        o.x = f2bf(pp.x); o.y = f2bf(pp.y); o.z = f2bf(pp.z); o.w = f2bf(pp.w);
        ((us4*)p.Wihb)[i] = o;
        float4 q = whf[i];
        o.x = f2bf(q.x); o.y = f2bf(q.y); o.z = f2bf(q.z); o.w = f2bf(q.w);
        ((us4*)p.Whhb)[i] = o;
        o.x = f2bf(pp.x + q.x); o.y = f2bf(pp.y + q.y);
        o.z = f2bf(pp.z + q.z); o.w = f2bf(pp.w + q.w);
        ((us4*)p.Wsmb)[i] = o;
      }
    }
    p.pacc[gid] = 0.f;
    if (gid < 1024) p.bias[gid] = p.bih[gid] + p.bhh[gid];
    if (gid < 4608) p.barrier[gid] = 0u;
  }
  grid.sync();

  // ---- FF phases ----
  gemm_stream4(p.Xb, p.W1b, 4096, p.b1, p.X1b, nullptr, 0, lds, w, l, wm, wn,
               lhi, llo, m0f, n0f);
  gbar(p.barrier, 1, t, bid);
  gemm_stream4(p.X1b, p.W2b, 1024, p.b2, p.Xlb, nullptr, 0, lds, w, l, wm, wn,
               lhi, llo, m0f, n0f);
  gbar(p.barrier, 2, t, bid);
  gemm_stream4(p.Xlb, p.Wihb, 1024, nullptr, nullptr, p.xw, 2, lds, w, l, wm,
               wn, lhi, llo, m0f, n0f);
  gbar(p.barrier, 3, t, bid);

  // ---- publish XCD id for locality check ----
  unsigned xccid;
  __asm__ __volatile__("s_getreg_b32 %0, hwreg(HW_REG_XCC_ID)" : "=s"(xccid));
  if (t == 0)
    __hip_atomic_store(&p.barrier[1024 + (mgrp << 4) + nblk],
                       1000u + (xccid & 15u), __ATOMIC_RELAXED,
                       __HIP_MEMORY_SCOPE_AGENT);

  // ---- resident FULL Wsum slab (rows n0r..n0r+63, K=1024, 128 KB) ----
  short* slab = (short*)lds;
  {
    const ushort_t* Wn = p.Wsmb + ((size_t)n0r << 10);
#pragma unroll
    for (int i = 0; i < 32; ++i) {
      int c = t + (i << 8);
      int r = c >> 7, cc = c & 127;
      int pc = (cc & ~7) | ((cc & 7) ^ (r & 7));
      short8 v = *(const short8*)(Wn + ((size_t)r << 10) + (cc << 3));
      *(short8*)(slab + (r << 10) + (pc << 3)) = v;
    }
  }
  gbar(p.barrier, 4, t, bid);  // publishes xcd ids; also covers slab sync

  // ---- m-group locality check ----
  unsigned myx = 0u;
  if (l < 16)
    myx = __hip_atomic_load(&p.barrier[1024 + (mgrp << 4) + l],
                            __ATOMIC_RELAXED, __HIP_MEMORY_SCOPE_AGENT);
  unsigned x0 = __shfl(myx, 0);
  const bool local = __all((l >= 16) || (myx == x0));

  short* hring = (short*)(lds + 131072);  // 6 slots x 4KB
  ushort_t* Hb[2] = {p.Hb0, p.Hb1};
  unsigned* mbar = p.barrier + 320 + (mgrp << 4);

  int gnb[2], gmv[2];
#pragma unroll
  for (int tn = 0; tn < 2; ++tn)
    gnb[tn] = n0r + (wn << 5) + (tn << 4) + (lhi << 2);
#pragma unroll
  for (int tm = 0; tm < 2; ++tm)
    gmv[tm] = m0r + (wm << 5) + (tm << 4) + llo;
  float bias_r[2][4], wa_r[2][4], xw_r[2][2][4];
#pragma unroll
  for (int tn = 0; tn < 2; ++tn)
#pragma unroll
    for (int i = 0; i < 4; ++i) {
      bias_r[tn][i] = p.bias[gnb[tn] + i];
      wa_r[tn][i] = p.Wa[gnb[tn] + i];
    }
#pragma unroll
  for (int tm = 0; tm < 2; ++tm)
#pragma unroll
    for (int tn = 0; tn < 2; ++tn)
#pragma unroll
      for (int i = 0; i < 4; ++i)
        xw_r[tm][tn][i] = p.xw[((size_t)gmv[tm] << 10) + gnb[tn] + i];

  const int rot = nblk << 1;
  const float ba0 = p.ba[0];

  auto runsteps = [&](auto LC) {
    constexpr bool LOCAL = (decltype(LC)::value != 0);
    constexpr int AUXH = LOCAL ? 1 : 17;  // sc0 (L2-local) vs sc0|sc1 (MALL)
    for (int st = 0; st < 64; ++st) {
      const ushort_t* hbase =
          ((st == 0) ? p.Xlb : Hb[st & 1]) + ((size_t)m0r << 10);
      bool flag = st && !(st & 15);
      floatx4 acc[2][2];  // [tn][tm]
#pragma unroll
      for (int i = 0; i < 2; ++i)
#pragma unroll
        for (int j = 0; j < 2; ++j) acc[i][j] = (floatx4){0.f, 0.f, 0.f, 0.f};

      if (!flag) {
#pragma unroll
        for (int j = 0; j < 4; ++j)
          stage_chunk<AUXH>(hbase + (((rot + j) & 31) << 5), hring + j * 2048,
                            w, l);
        static_for<32>([&](auto icc) {
          constexpr int c = decltype(icc)::value;
          waitvm<nwa(c)>();
          BAR();
          CBARRIER();
          if (c + 4 < 32)
            stage_chunk<AUXH>(hbase + (((rot + c + 4) & 31) << 5),
                              hring + ((c + 4) % 6) * 2048, w, l);
          const short* hslot = hring + (c % 6) * 2048;
          int kc = (rot + c) & 31;
          short8 afr[2], bfr[2];
#pragma unroll
          for (int tn = 0; tn < 2; ++tn) {
            int na = (wn << 5) + (tn << 4) + llo;
            int u = (kc << 2) + lhi;
            int pu = (u & ~7) | ((u & 7) ^ (na & 7));
            afr[tn] = *(const short8*)(slab + (na << 10) + (pu << 3));
          }
#pragma unroll
          for (int tm = 0; tm < 2; ++tm) {
            int mb = (wm << 5) + (tm << 4) + llo;
            bfr[tm] = *(const short8*)(hslot + mb * 32 +
                                       ((lhi ^ ((mb >> 1) & 3)) << 3));
          }
#pragma unroll
          for (int tn = 0; tn < 2; ++tn)
#pragma unroll
            for (int tm = 0; tm < 2; ++tm)
              acc[tn][tm] = __builtin_amdgcn_mfma_f32_16x16x32_bf16(
                  afr[tn], bfr[tm], acc[tn][tm], 0, 0, 0);
        });
      } else {
        const ushort_t* wbase = p.Whhb + ((size_t)n0r << 10);
#pragma unroll
        for (int j = 0; j < 2; ++j) {
          int kc = (rot + j) & 31;
          stage_chunk<0>(wbase + (kc << 5), hring + j * 2048, w, l);
          stage_chunk<AUXH>(hbase + (kc << 5), hring + (3 + j) * 2048, w, l);
        }
        static_for<32>([&](auto icc) {
          constexpr int c = decltype(icc)::value;
          waitvm<nwb(c)>();
          BAR();
          CBARRIER();
          if (c + 2 < 32) {
            int kc = (rot + c + 2) & 31;
            stage_chunk<0>(wbase + (kc << 5), hring + ((c + 2) % 3) * 2048, w,
                           l);
            stage_chunk<AUXH>(hbase + (kc << 5),
                              hring + (3 + (c + 2) % 3) * 2048, w, l);
          }
          const short* wslot = hring + (c % 3) * 2048;
          const short* hslot = hring + (3 + c % 3) * 2048;
          short8 afr[2], bfr[2];
#pragma unroll
          for (int tn = 0; tn < 2; ++tn) {
            int na = (wn << 5) + (tn << 4) + llo;
            afr[tn] = *(const short8*)(wslot + na * 32 +
                                       ((lhi ^ ((na >> 1) & 3)) << 3));
          }
#pragma unroll
          for (int tm = 0; tm < 2; ++tm) {
            int mb = (wm << 5) + (tm << 4) + llo;
            bfr[tm] = *(const short8*)(hslot + mb * 32 +
                                       ((lhi ^ ((mb >> 1) & 3)) << 3));
          }
#pragma unroll
          for (int tn = 0; tn < 2; ++tn)
#pragma unroll
            for (int tm = 0; tm < 2; ++tm)
              acc[tn][tm] = __builtin_amdgcn_mfma_f32_16x16x32_bf16(
                  afr[tn], bfr[tm], acc[tn][tm], 0, 0, 0);
        });
      }

      // ---- epilogue ----
      bool last = (st == 63);
      ushort_t* Hnext = Hb[(st + 1) & 1];
      float hv[2][2][4];  // [tn][tm][i]
#pragma unroll
      for (int tn = 0; tn < 2; ++tn)
#pragma unroll
        for (int tm = 0; tm < 2; ++tm)
#pragma unroll
          for (int i = 0; i < 4; ++i) {
            float v = acc[tn][tm][i] + bias_r[tn][i];
            if (flag) v += xw_r[tm][tn][i];
            hv[tn][tm][i] = fast_tanh(v);
          }
      if (!last) {
#pragma unroll
        for (int tn = 0; tn < 2; ++tn)
#pragma unroll
          for (int tm = 0; tm < 2; ++tm) {
            unsigned long long pk =
                (unsigned long long)f2bf(hv[tn][tm][0]) |
                ((unsigned long long)f2bf(hv[tn][tm][1]) << 16) |
                ((unsigned long long)f2bf(hv[tn][tm][2]) << 32) |
                ((unsigned long long)f2bf(hv[tn][tm][3]) << 48);
            ushort_t* dst = Hnext + ((size_t)gmv[tm] << 10) + gnb[tn];
            if (LOCAL) {
              __asm__ __volatile__("global_store_dwordx2 %0, %1, off"
                                   :
                                   : "v"(dst), "v"(pk)
                                   : "memory");
            } else {
              __asm__ __volatile__("global_store_dwordx2 %0, %1, off sc0 sc1"
                                   :
                                   : "v"(dst), "v"(pk)
                                   : "memory");
            }
          }
      } else {
#pragma unroll
        for (int tn = 0; tn < 2; ++tn)
#pragma unroll
          for (int tm = 0; tm < 2; ++tm) {
            float4 o = make_float4(hv[tn][tm][0], hv[tn][tm][1], hv[tn][tm][2],
                                   hv[tn][tm][3]);
            *(float4*)(p.hxout + ((size_t)gmv[tm] << 10) + gnb[tn]) = o;
          }
      }
      // actor partial into pacc
#pragma unroll
      for (int tm = 0; tm < 2; ++tm) {
        float s = 0.f;
#pragma unroll
        for (int tn = 0; tn < 2; ++tn)
#pragma unroll
          for (int i = 0; i < 4; ++i) s += hv[tn][tm][i] * wa_r[tn][i];
        s += __shfl_xor(s, 16);
        s += __shfl_xor(s, 32);
        if (l < 16) atomicAdd(&p.pacc[(st << 10) + gmv[tm]], s);
      }

      // ---- m-group barrier (16 blocks) ----
      if (!last) {
        WAITVM(0);
        __syncthreads();
        if (t == 0) {
          atomicAdd(mbar, 1u);
          unsigned tgt = (unsigned)(st + 1) << 4;
          while (__hip_atomic_load(mbar, __ATOMIC_RELAXED,
                                   __HIP_MEMORY_SCOPE_AGENT) < tgt)
            __builtin_amdgcn_s_sleep(1);
        }
        __syncthreads();
      } else {
        WAITVM(0);
      }
    }
  };
  if (local) runsteps(Int<1>{});
  else runsteps(Int<0>{});

  gbar(p.barrier, 5, t, bid);
  p.probs[gid] = fast_sigmoid(p.pacc[gid] + ba0);
}

extern "C" void kernel_launch(void* const* d_in, const int* in_sizes, int n_in,
                              void* d_out, int out_size, void* d_ws,
                              size_t ws_size, hipStream_t stream) {
  char* ws = (char*)d_ws;
  KP p;
  p.x = (const float*)d_in[0];
  p.W1 = (const float*)d_in[1];
  p.b1 = (const float*)d_in[2];
  p.W2 = (const float*)d_in[3];
  p.b2 = (const float*)d_in[4];
  p.Wih = (const float*)d_in[5];
  p.Whh = (const float*)d_in[6];
  p.bih = (const float*)d_in[7];
  p.bhh = (const float*)d_in[8];
  p.Wa = (const float*)d_in[9];
  p.ba = (const float*)d_in[10];
  p.Xb = (ushort_t*)(ws);
  p.W1b = (ushort_t*)(ws + ((size_t)8 << 20));
  p.W2b = (ushort_t*)(ws + ((size_t)16 << 20));
  p.Wihb = (ushort_t*)(ws + ((size_t)18 << 20));
  p.Whhb = (ushort_t*)(ws + ((size_t)20 << 20));
  p.Wsmb = (ushort_t*)(ws + ((size_t)22 << 20));
  p.X1b = (ushort_t*)(ws + ((size_t)24 << 20));
  p.Xlb = (ushort_t*)(ws + ((size_t)26 << 20));
  p.Hb0 = (ushort_t*)(ws + ((size_t)28 << 20));
  p.Hb1 = (ushort_t*)(ws + ((size_t)30 << 20));
  p.xw = (float*)(ws + ((size_t)32 << 20));
  p.bias = (float*)(ws + ((size_t)36 << 20));
  p.pacc = (float*)(ws + ((size_t)36 << 20) + 4096);
  p.barrier = (unsigned*)(ws + ((size_t)36 << 20) + 4096 + 262144);
  p.probs = (float*)d_out;
  p.hxout = (float*)d_out + 65536;

  (void)hipFuncSetAttribute((const void*)fused_rnn,
                            hipFuncAttributeMaxDynamicSharedMemorySize, 155648);
  void* args[] = {&p};
  (void)hipLaunchCooperativeKernel((const void*)fused_rnn, dim3(256), dim3(256),
                                   args, 155648, stream);
}